// Round 3
// baseline (1935.456 us; speedup 1.0000x reference)
//
#include <hip/hip_runtime.h>

#define NN 100000
#define NE 1600000
#define DD 64
#define NL 3
#define NG 128
#define BN_EPS 1e-5f

// ---------------- dtype detection: int64 vs int32 index arrays ----------------
// int64 read as int32: every odd word is a zero high-word (ids >= 0, < 2^31).
// edge_index: sample odd words at the front (random node ids -> nonzero whp).
// batch: sorted starting at 0, so sample odd words near the END of the first NN
//        words (int32 -> values ~127 nonzero; int64 -> high words = 0).
__global__ __launch_bounds__(256) void detect_kernel(const int* __restrict__ ei,
                                                     const int* __restrict__ batch,
                                                     int* __restrict__ flags) {
    __shared__ int s_e, s_b;
    if (threadIdx.x == 0) { s_e = 0; s_b = 0; }
    __syncthreads();
    for (int i = threadIdx.x; i < 512; i += 256) {
        if (ei[2 * i + 1] != 0) atomicOr(&s_e, 1);
        if (batch[NN - 1024 + 2 * i + 1] != 0) atomicOr(&s_b, 1);
    }
    __syncthreads();
    if (threadIdx.x == 0) { flags[0] = s_e; flags[1] = s_b; }  // 1 = int32, 0 = int64
}

__device__ __forceinline__ int ld_src(const int* ei, int e, int is32) {
    return is32 ? ei[e] : ei[2 * e];
}
__device__ __forceinline__ int ld_dst(const int* ei, int e, int is32) {
    return is32 ? ei[NE + e] : ei[2 * NE + 2 * e];
}
__device__ __forceinline__ int ld_batch(const int* b, int n, int is32) {
    return is32 ? b[n] : b[2 * n];
}

// ---------------- degree / norm ----------------
__global__ __launch_bounds__(256) void deg_kernel(const int* __restrict__ ei,
                                                  const int* __restrict__ flags,
                                                  float* __restrict__ deg) {
    int is32 = flags[0];
    int e = blockIdx.x * 256 + threadIdx.x;
    if (e < NE) atomicAdd(&deg[ld_dst(ei, e, is32)], 1.0f);
}

__global__ __launch_bounds__(256) void dinv_kernel(float* __restrict__ deg) {
    int i = blockIdx.x * 256 + threadIdx.x;
    if (i < NN) deg[i] = rsqrtf(deg[i] + 1.0f);  // +1 self-loop; deg >= 1 always
}

// ---------------- t = h @ W  (W column register-resident per lane) ----------------
__global__ __launch_bounds__(256) void gemm_kernel(const float* __restrict__ h,
                                                   const float* __restrict__ W,
                                                   float* __restrict__ t) {
    int c = threadIdx.x & 63;
    float w[DD];
#pragma unroll
    for (int k = 0; k < DD; ++k) w[k] = W[k * DD + c];

    int wave = blockIdx.x * (blockDim.x >> 6) + (threadIdx.x >> 6);
    int nwaves = gridDim.x * (blockDim.x >> 6);
    for (int r = wave; r < NN; r += nwaves) {
        const float4* hrow = (const float4*)(h + (size_t)r * DD);
        float acc = 0.f;
#pragma unroll
        for (int kk = 0; kk < DD / 4; ++kk) {
            float4 hv = hrow[kk];  // wave-uniform address -> scalar broadcast
            acc += hv.x * w[4 * kk] + hv.y * w[4 * kk + 1] +
                   hv.z * w[4 * kk + 2] + hv.w * w[4 * kk + 3];
        }
        t[(size_t)r * DD + c] = acc;
    }
}

// ---------------- agg init: self-loop + bias ----------------
__global__ __launch_bounds__(256) void init_agg_kernel(const float* __restrict__ t,
                                                       const float* __restrict__ dinv,
                                                       const float* __restrict__ b,
                                                       float* __restrict__ agg) {
    int i = blockIdx.x * 256 + threadIdx.x;
    if (i >= NN * DD) return;
    int n = i >> 6, f = i & 63;
    float di = dinv[n];
    agg[i] = t[i] * di * di + b[f];
}

// ---------------- edge scatter: agg[dst] += t[src]*dinv[src]*dinv[dst] ----------------
__global__ __launch_bounds__(256) void scatter_kernel(const float* __restrict__ t,
                                                      const float* __restrict__ dinv,
                                                      const int* __restrict__ ei,
                                                      const int* __restrict__ flags,
                                                      float* __restrict__ agg) {
    int is32 = flags[0];
    int gid = blockIdx.x * 256 + threadIdx.x;  // NE*64 = 102.4M < 2^31
    int e = gid >> 6, f = gid & 63;
    if (e >= NE) return;
    int s = ld_src(ei, e, is32), d = ld_dst(ei, e, is32);
    float nw = dinv[s] * dinv[d];
    atomicAdd(&agg[(size_t)d * DD + f], t[(size_t)s * DD + f] * nw);
}

// ---------------- BN stats: per-feature sum & sumsq ----------------
__global__ __launch_bounds__(256) void bn_stats_kernel(const float* __restrict__ agg,
                                                       float* __restrict__ stats) {
    __shared__ float s_sum[256], s_sq[256];
    int f = threadIdx.x & 63, rg = threadIdx.x >> 6;
    float sum = 0.f, sq = 0.f;
    for (int n = blockIdx.x * 4 + rg; n < NN; n += gridDim.x * 4) {
        float v = agg[(size_t)n * DD + f];
        sum += v;
        sq += v * v;
    }
    s_sum[threadIdx.x] = sum;
    s_sq[threadIdx.x] = sq;
    __syncthreads();
    if (threadIdx.x < 64) {
        sum = s_sum[f] + s_sum[64 + f] + s_sum[128 + f] + s_sum[192 + f];
        sq = s_sq[f] + s_sq[64 + f] + s_sq[128 + f] + s_sq[192 + f];
        atomicAdd(&stats[f], sum);
        atomicAdd(&stats[DD + f], sq);
    }
}

__global__ __launch_bounds__(64) void bn_finalize_kernel(float* __restrict__ stats,
                                                         const float* __restrict__ gamma,
                                                         const float* __restrict__ beta) {
    int f = threadIdx.x;
    float mean = stats[f] / (float)NN;
    float var = stats[DD + f] / (float)NN - mean * mean;
    var = fmaxf(var, 0.f);
    float sc = gamma[f] * rsqrtf(var + BN_EPS);
    stats[2 * DD + f] = sc;
    stats[3 * DD + f] = beta[f] - mean * sc;
}

__global__ __launch_bounds__(256) void bn_apply_kernel(float* __restrict__ h,
                                                       const float* __restrict__ stats) {
    int i = blockIdx.x * 256 + threadIdx.x;
    if (i >= NN * DD) return;
    int f = i & 63;
    float v = h[i] * stats[2 * DD + f] + stats[3 * DD + f];
    h[i] = fmaxf(v, 0.f);
}

// ---------------- global mean pool (batch sorted -> run-length flush) ----------------
#define POOL_CHUNK 512
__global__ __launch_bounds__(256) void pool_kernel(const float* __restrict__ h,
                                                   const int* __restrict__ batch,
                                                   const int* __restrict__ flags,
                                                   float* __restrict__ pool) {
    int is32 = flags[1];
    int f = threadIdx.x & 63, rg = threadIdx.x >> 6;
    int base = blockIdx.x * POOL_CHUNK;
    float acc = 0.f;
    int cur = -1;
    for (int i = rg; i < POOL_CHUNK; i += 4) {
        int n = base + i;
        if (n >= NN) break;
        int g = ld_batch(batch, n, is32);
        if (g != cur) {
            if (cur >= 0) atomicAdd(&pool[(size_t)cur * DD + f], acc);
            acc = 0.f;
            cur = g;
        }
        acc += h[(size_t)n * DD + f];
    }
    if (cur >= 0) atomicAdd(&pool[(size_t)cur * DD + f], acc);
}

__global__ __launch_bounds__(256) void counts_kernel(const int* __restrict__ batch,
                                                     const int* __restrict__ flags,
                                                     float* __restrict__ counts) {
    int is32 = flags[1];
    int n = blockIdx.x * 256 + threadIdx.x;
    if (n < NN) atomicAdd(&counts[ld_batch(batch, n, is32)], 1.0f);
}

__global__ __launch_bounds__(256) void final_kernel(const float* __restrict__ pool,
                                                    const float* __restrict__ counts,
                                                    float* __restrict__ out) {
    int i = blockIdx.x * 256 + threadIdx.x;
    if (i < NG * DD) {
        int g = i >> 6;
        out[i] = pool[i] / fmaxf(counts[g], 1.0f);
    }
}

extern "C" void kernel_launch(void* const* d_in, const int* in_sizes, int n_in,
                              void* d_out, int out_size, void* d_ws, size_t ws_size,
                              hipStream_t stream) {
    const float* x = (const float*)d_in[0];       // [NN, DD] f32
    const int* edge_index = (const int*)d_in[1];  // [2, NE] int32 (or int64, detected)
    const int* batch = (const int*)d_in[2];       // [NN] int32 (or int64, detected)
    const float* Ws = (const float*)d_in[3];      // [3,64,64] f32
    const float* bs = (const float*)d_in[4];      // [3,64] f32
    const float* gammas = (const float*)d_in[5];  // [3,64] f32
    const float* betas = (const float*)d_in[6];   // [3,64] f32
    float* out = (float*)d_out;                   // [NG, DD] f32

    // workspace layout (f32)
    float* h = (float*)d_ws;              // 6,400,000 floats (aliased as agg)
    float* t = h + (size_t)NN * DD;       // 6,400,000 floats
    float* dinv = t + (size_t)NN * DD;    // 100,000 floats (deg then dinv in place)
    float* stats = dinv + NN;             // 256 floats: sum, sumsq, scale, shift
    float* pool = stats + 256;            // 8192 floats
    float* counts = pool + (size_t)NG * DD;  // 128 floats
    int* flags = (int*)(counts + NG);     // 2 ints: edge_is32, batch_is32

    // zero the accumulators (ws is poisoned 0xAA each call)
    hipMemsetAsync(dinv, 0, NN * sizeof(float), stream);
    hipMemsetAsync(pool, 0, (NG * DD + NG) * sizeof(float), stream);  // pool + counts

    detect_kernel<<<1, 256, 0, stream>>>(edge_index, batch, flags);
    deg_kernel<<<(NE + 255) / 256, 256, 0, stream>>>(edge_index, flags, dinv);
    dinv_kernel<<<(NN + 255) / 256, 256, 0, stream>>>(dinv);

    for (int l = 0; l < NL; ++l) {
        const float* hin = (l == 0) ? x : h;
        gemm_kernel<<<1024, 256, 0, stream>>>(hin, Ws + (size_t)l * DD * DD, t);
        init_agg_kernel<<<(NN * DD + 255) / 256, 256, 0, stream>>>(t, dinv, bs + l * DD, h);
        scatter_kernel<<<(NE * 64) / 256, 256, 0, stream>>>(t, dinv, edge_index, flags, h);
        hipMemsetAsync(stats, 0, 2 * DD * sizeof(float), stream);
        bn_stats_kernel<<<256, 256, 0, stream>>>(h, stats);
        bn_finalize_kernel<<<1, 64, 0, stream>>>(stats, gammas + l * DD, betas + l * DD);
        bn_apply_kernel<<<(NN * DD + 255) / 256, 256, 0, stream>>>(h, stats);
    }

    pool_kernel<<<(NN + POOL_CHUNK - 1) / POOL_CHUNK, 256, 0, stream>>>(h, batch, flags, pool);
    counts_kernel<<<(NN + 255) / 256, 256, 0, stream>>>(batch, flags, counts);
    final_kernel<<<(NG * DD + 255) / 256, 256, 0, stream>>>(pool, counts, out);
}

// Round 4
// 1366.229 us; speedup vs baseline: 1.4166x; 1.4166x over previous
//
#include <hip/hip_runtime.h>

#define NN 100000
#define NE 1600000
#define DD 64
#define NL 3
#define NG 128
#define BN_EPS 1e-5f
#define NBLK_GATHER 2048

// ---------------- dtype detection: int64 vs int32 index arrays ----------------
__global__ __launch_bounds__(256) void detect_kernel(const int* __restrict__ ei,
                                                     const int* __restrict__ batch,
                                                     int* __restrict__ flags) {
    __shared__ int s_e, s_b;
    if (threadIdx.x == 0) { s_e = 0; s_b = 0; }
    __syncthreads();
    for (int i = threadIdx.x; i < 512; i += 256) {
        if (ei[2 * i + 1] != 0) atomicOr(&s_e, 1);
        if (batch[NN - 1024 + 2 * i + 1] != 0) atomicOr(&s_b, 1);
    }
    __syncthreads();
    if (threadIdx.x == 0) { flags[0] = s_e; flags[1] = s_b; }  // 1 = int32, 0 = int64
}

__device__ __forceinline__ int ld_src(const int* ei, int e, int is32) {
    return is32 ? ei[e] : ei[2 * e];
}
__device__ __forceinline__ int ld_dst(const int* ei, int e, int is32) {
    return is32 ? ei[NE + e] : ei[2 * NE + 2 * e];
}
__device__ __forceinline__ int ld_batch(const int* b, int n, int is32) {
    return is32 ? b[n] : b[2 * n];
}

// ---------------- degree (int) ----------------
__global__ __launch_bounds__(256) void deg_kernel(const int* __restrict__ ei,
                                                  const int* __restrict__ flags,
                                                  int* __restrict__ deg_cnt) {
    int is32 = flags[0];
    int e = blockIdx.x * 256 + threadIdx.x;
    if (e < NE) atomicAdd(&deg_cnt[ld_dst(ei, e, is32)], 1);
}

__global__ __launch_bounds__(256) void dinv_kernel(const int* __restrict__ deg_cnt,
                                                   float* __restrict__ dinv) {
    int i = blockIdx.x * 256 + threadIdx.x;
    if (i < NN) dinv[i] = rsqrtf((float)deg_cnt[i] + 1.0f);  // +1 self-loop
}

// ---------------- exclusive scan of degrees -> rowptr; zeros deg_cnt ----------------
#define SCAN_CHUNK 98  // ceil(100000/1024)
__global__ __launch_bounds__(1024) void scan_kernel(int* __restrict__ deg_cnt,
                                                    int* __restrict__ rowptr) {
    __shared__ int s[1024];
    int tid = threadIdx.x;
    int beg = tid * SCAN_CHUNK;
    int end = min(beg + SCAN_CHUNK, NN);
    int sum = 0;
    for (int i = beg; i < end; ++i) sum += deg_cnt[i];
    s[tid] = sum;
    for (int off = 1; off < 1024; off <<= 1) {
        __syncthreads();
        int add = (tid >= off) ? s[tid - off] : 0;
        __syncthreads();
        s[tid] += add;
    }
    __syncthreads();
    int base = s[tid] - sum;  // exclusive prefix
    for (int i = beg; i < end; ++i) {
        rowptr[i] = base;
        base += deg_cnt[i];
        deg_cnt[i] = 0;  // reuse as fill cursor
    }
    if (tid == 1023) rowptr[NN] = s[1023];
}

// ---------------- CSR fill: interleaved (src, weight) ----------------
__global__ __launch_bounds__(256) void fill_kernel(const int* __restrict__ ei,
                                                   const int* __restrict__ flags,
                                                   const float* __restrict__ dinv,
                                                   const int* __restrict__ rowptr,
                                                   int* __restrict__ cursor,
                                                   int2* __restrict__ csw) {
    int is32 = flags[0];
    int e = blockIdx.x * 256 + threadIdx.x;
    if (e >= NE) return;
    int s = ld_src(ei, e, is32), d = ld_dst(ei, e, is32);
    int pos = rowptr[d] + atomicAdd(&cursor[d], 1);
    float w = dinv[s] * dinv[d];
    csw[pos] = make_int2(s, __float_as_int(w));
}

// ---------------- t = h @ W  (W column register-resident per lane) ----------------
__global__ __launch_bounds__(256) void gemm_kernel(const float* __restrict__ h,
                                                   const float* __restrict__ W,
                                                   float* __restrict__ t) {
    int c = threadIdx.x & 63;
    float w[DD];
#pragma unroll
    for (int k = 0; k < DD; ++k) w[k] = W[k * DD + c];

    int wave = blockIdx.x * (blockDim.x >> 6) + (threadIdx.x >> 6);
    int nwaves = gridDim.x * (blockDim.x >> 6);
    for (int r = wave; r < NN; r += nwaves) {
        const float4* hrow = (const float4*)(h + (size_t)r * DD);
        float acc = 0.f;
#pragma unroll
        for (int kk = 0; kk < DD / 4; ++kk) {
            float4 hv = hrow[kk];  // wave-uniform -> cacheline broadcast
            acc += hv.x * w[4 * kk] + hv.y * w[4 * kk + 1] +
                   hv.z * w[4 * kk + 2] + hv.w * w[4 * kk + 3];
        }
        t[(size_t)r * DD + c] = acc;
    }
}

// ---------------- gather: agg = self + bias + neighbor sum; partial BN stats ----------------
__global__ __launch_bounds__(256) void gather_kernel(const float* __restrict__ t,
                                                     const float* __restrict__ dinv,
                                                     const float* __restrict__ bias,
                                                     const int* __restrict__ rowptr,
                                                     const int2* __restrict__ csw,
                                                     float* __restrict__ h,
                                                     float* __restrict__ part) {
    int f = threadIdx.x & 63;
    int wave = blockIdx.x * 4 + (threadIdx.x >> 6);
    float bb = bias[f];
    float sum = 0.f, sq = 0.f;
    for (int d = wave; d < NN; d += NBLK_GATHER * 4) {
        float di = dinv[d];
        float acc = t[d * DD + f] * di * di + bb;
        int j = rowptr[d], jend = rowptr[d + 1];
        for (; j + 4 <= jend; j += 4) {
            int2 a0 = csw[j], a1 = csw[j + 1], a2 = csw[j + 2], a3 = csw[j + 3];
            float v0 = t[a0.x * DD + f];
            float v1 = t[a1.x * DD + f];
            float v2 = t[a2.x * DD + f];
            float v3 = t[a3.x * DD + f];
            acc += v0 * __int_as_float(a0.y) + v1 * __int_as_float(a1.y) +
                   v2 * __int_as_float(a2.y) + v3 * __int_as_float(a3.y);
        }
        for (; j < jend; ++j) {
            int2 a = csw[j];
            acc += t[a.x * DD + f] * __int_as_float(a.y);
        }
        h[d * DD + f] = acc;
        sum += acc;
        sq += acc * acc;
    }
    __shared__ float s_sum[256], s_sq[256];
    s_sum[threadIdx.x] = sum;
    s_sq[threadIdx.x] = sq;
    __syncthreads();
    if (threadIdx.x < 64) {
        sum = s_sum[f] + s_sum[64 + f] + s_sum[128 + f] + s_sum[192 + f];
        sq = s_sq[f] + s_sq[64 + f] + s_sq[128 + f] + s_sq[192 + f];
        part[blockIdx.x * 128 + f] = sum;
        part[blockIdx.x * 128 + 64 + f] = sq;
    }
}

// ---------------- BN finalize: reduce partials -> scale/shift ----------------
__global__ __launch_bounds__(256) void bn_finalize_kernel(const float* __restrict__ part,
                                                          const float* __restrict__ gamma,
                                                          const float* __restrict__ beta,
                                                          float* __restrict__ stats_l) {
    __shared__ float s_sum[256], s_sq[256];
    int f = threadIdx.x & 63, g = threadIdx.x >> 6;
    float S = 0.f, Q = 0.f;
    for (int bk = g; bk < NBLK_GATHER; bk += 4) {
        S += part[bk * 128 + f];
        Q += part[bk * 128 + 64 + f];
    }
    s_sum[threadIdx.x] = S;
    s_sq[threadIdx.x] = Q;
    __syncthreads();
    if (threadIdx.x < 64) {
        S = s_sum[f] + s_sum[64 + f] + s_sum[128 + f] + s_sum[192 + f];
        Q = s_sq[f] + s_sq[64 + f] + s_sq[128 + f] + s_sq[192 + f];
        float mean = S / (float)NN;
        float var = fmaxf(Q / (float)NN - mean * mean, 0.f);
        float sc = gamma[f] * rsqrtf(var + BN_EPS);
        stats_l[f] = sc;
        stats_l[64 + f] = beta[f] - mean * sc;
    }
}

// ---------------- BN apply + ReLU (in place) ----------------
__global__ __launch_bounds__(256) void bn_apply_kernel(float* __restrict__ h,
                                                       const float* __restrict__ stats_l) {
    int i = blockIdx.x * 256 + threadIdx.x;
    if (i >= NN * DD) return;
    int f = i & 63;
    float v = h[i] * stats_l[f] + stats_l[64 + f];
    h[i] = fmaxf(v, 0.f);
}

// ---------------- pool: fused BN-apply(layer3) + ReLU + mean-pool + counts ----------------
#define POOL_CHUNK 512
__global__ __launch_bounds__(256) void pool_kernel(const float* __restrict__ hraw,
                                                   const float* __restrict__ stats_l,
                                                   const int* __restrict__ batch,
                                                   const int* __restrict__ flags,
                                                   float* __restrict__ pool,
                                                   float* __restrict__ counts) {
    int is32 = flags[1];
    int f = threadIdx.x & 63, rg = threadIdx.x >> 6;
    float sc = stats_l[f], sh = stats_l[64 + f];
    int base = blockIdx.x * POOL_CHUNK;
    float acc = 0.f, cnt = 0.f;
    int cur = -1;
    for (int i = rg; i < POOL_CHUNK; i += 4) {
        int n = base + i;
        if (n >= NN) break;
        int g = ld_batch(batch, n, is32);
        if (g != cur) {
            if (cur >= 0) {
                atomicAdd(&pool[cur * DD + f], acc);
                if (f == 0) atomicAdd(&counts[cur], cnt);
            }
            acc = 0.f;
            cnt = 0.f;
            cur = g;
        }
        acc += fmaxf(hraw[(size_t)n * DD + f] * sc + sh, 0.f);
        cnt += 1.f;
    }
    if (cur >= 0) {
        atomicAdd(&pool[cur * DD + f], acc);
        if (f == 0) atomicAdd(&counts[cur], cnt);
    }
}

__global__ __launch_bounds__(256) void final_kernel(const float* __restrict__ pool,
                                                    const float* __restrict__ counts,
                                                    float* __restrict__ out) {
    int i = blockIdx.x * 256 + threadIdx.x;
    if (i < NG * DD) {
        int g = i >> 6;
        out[i] = pool[i] / fmaxf(counts[g], 1.0f);
    }
}

extern "C" void kernel_launch(void* const* d_in, const int* in_sizes, int n_in,
                              void* d_out, int out_size, void* d_ws, size_t ws_size,
                              hipStream_t stream) {
    const float* x = (const float*)d_in[0];       // [NN, DD] f32
    const int* edge_index = (const int*)d_in[1];  // [2, NE] int (width detected)
    const int* batch = (const int*)d_in[2];       // [NN] int (width detected)
    const float* Ws = (const float*)d_in[3];      // [3,64,64]
    const float* bs = (const float*)d_in[4];      // [3,64]
    const float* gammas = (const float*)d_in[5];  // [3,64]
    const float* betas = (const float*)d_in[6];   // [3,64]
    float* out = (float*)d_out;                   // [NG, DD]

    // workspace layout (keep csw 8-byte aligned: all preceding counts are even)
    float* h = (float*)d_ws;                   // 6,400,000 f
    float* t = h + (size_t)NN * DD;            // 6,400,000 f
    int2* csw = (int2*)(t + (size_t)NN * DD);  // NE int2 (12.8 MB)
    float* dinv = (float*)(csw + NE);          // 100,000 f
    int* deg_cnt = (int*)(dinv + NN);          // 100,000 i (also fill cursor)
    int* rowptr = deg_cnt + NN;                // 100,001 i
    float* part = (float*)(rowptr + NN + 1);   // NBLK_GATHER*128 f
    float* stats = part + NBLK_GATHER * 128;   // 3*128 f (sc, sh per layer)
    float* pool = stats + NL * 128;            // 8192 f
    float* counts = pool + NG * DD;            // 128 f
    int* flags = (int*)(counts + NG);          // 2 i

    hipMemsetAsync(deg_cnt, 0, NN * sizeof(int), stream);
    hipMemsetAsync(pool, 0, (NG * DD + NG) * sizeof(float), stream);

    detect_kernel<<<1, 256, 0, stream>>>(edge_index, batch, flags);
    deg_kernel<<<(NE + 255) / 256, 256, 0, stream>>>(edge_index, flags, deg_cnt);
    dinv_kernel<<<(NN + 255) / 256, 256, 0, stream>>>(deg_cnt, dinv);
    scan_kernel<<<1, 1024, 0, stream>>>(deg_cnt, rowptr);
    fill_kernel<<<(NE + 255) / 256, 256, 0, stream>>>(edge_index, flags, dinv, rowptr,
                                                      deg_cnt, csw);

    for (int l = 0; l < NL; ++l) {
        const float* hin = (l == 0) ? x : h;
        if (l > 0)
            bn_apply_kernel<<<(NN * DD + 255) / 256, 256, 0, stream>>>(h, stats + (l - 1) * 128);
        gemm_kernel<<<1600, 256, 0, stream>>>(hin, Ws + (size_t)l * DD * DD, t);
        gather_kernel<<<NBLK_GATHER, 256, 0, stream>>>(t, dinv, bs + l * DD, rowptr, csw, h, part);
        bn_finalize_kernel<<<1, 256, 0, stream>>>(part, gammas + l * DD, betas + l * DD,
                                                  stats + l * 128);
    }

    pool_kernel<<<(NN + POOL_CHUNK - 1) / POOL_CHUNK, 256, 0, stream>>>(
        h, stats + 2 * 128, batch, flags, pool, counts);
    final_kernel<<<(NG * DD + 255) / 256, 256, 0, stream>>>(pool, counts, out);
}

// Round 5
// 1163.020 us; speedup vs baseline: 1.6642x; 1.1747x over previous
//
#include <hip/hip_runtime.h>

#define NN 100000
#define NE 1600000
#define DD 64
#define NL 3
#define NG 128
#define BN_EPS 1e-5f
#define NBLK_GATHER 2048
#define SCAN_BLK 98  // ceil(NN / 1024)

// ---------------- dtype detection: int64 vs int32 index arrays ----------------
__global__ __launch_bounds__(256) void detect_kernel(const int* __restrict__ ei,
                                                     const int* __restrict__ batch,
                                                     int* __restrict__ flags) {
    __shared__ int s_e, s_b;
    if (threadIdx.x == 0) { s_e = 0; s_b = 0; }
    __syncthreads();
    for (int i = threadIdx.x; i < 512; i += 256) {
        if (ei[2 * i + 1] != 0) atomicOr(&s_e, 1);
        if (batch[NN - 1024 + 2 * i + 1] != 0) atomicOr(&s_b, 1);
    }
    __syncthreads();
    if (threadIdx.x == 0) { flags[0] = s_e; flags[1] = s_b; }  // 1 = int32, 0 = int64
}

__device__ __forceinline__ int ld_src(const int* ei, int e, int is32) {
    return is32 ? ei[e] : ei[2 * e];
}
__device__ __forceinline__ int ld_dst(const int* ei, int e, int is32) {
    return is32 ? ei[NE + e] : ei[2 * NE + 2 * e];
}
__device__ __forceinline__ int ld_batch(const int* b, int n, int is32) {
    return is32 ? b[n] : b[2 * n];
}

// ---------------- degree (int) ----------------
__global__ __launch_bounds__(256) void deg_kernel(const int* __restrict__ ei,
                                                  const int* __restrict__ flags,
                                                  int* __restrict__ deg_cnt) {
    int is32 = flags[0];
    int e = blockIdx.x * 256 + threadIdx.x;
    if (e < NE) atomicAdd(&deg_cnt[ld_dst(ei, e, is32)], 1);
}

__global__ __launch_bounds__(256) void dinv_kernel(const int* __restrict__ deg_cnt,
                                                   float* __restrict__ dinv) {
    int i = blockIdx.x * 256 + threadIdx.x;
    if (i < NN) dinv[i] = rsqrtf((float)deg_cnt[i] + 1.0f);  // +1 self-loop
}

// ---------------- parallel exclusive scan of degrees -> rowptr ----------------
// phase 1: per-block (1024 nodes) totals
__global__ __launch_bounds__(256) void scan_part_kernel(const int* __restrict__ deg_cnt,
                                                        int* __restrict__ blocksum) {
    __shared__ int s[256];
    int base = blockIdx.x * 1024 + threadIdx.x * 4;
    int t = 0;
    if (base < NN) {  // NN % 4 == 0 -> whole int4 in-bounds
        int4 v = *(const int4*)(deg_cnt + base);
        t = v.x + v.y + v.z + v.w;
    }
    s[threadIdx.x] = t;
    __syncthreads();
    for (int off = 128; off > 0; off >>= 1) {
        if (threadIdx.x < off) s[threadIdx.x] += s[threadIdx.x + off];
        __syncthreads();
    }
    if (threadIdx.x == 0) blocksum[blockIdx.x] = s[0];
}

// phase 2: exclusive scan of the 98 block sums (in place); writes rowptr[NN]
__global__ __launch_bounds__(128) void scan_mid_kernel(int* __restrict__ blocksum,
                                                       int* __restrict__ rowptr) {
    __shared__ int s[128];
    int tid = threadIdx.x;
    int v = (tid < SCAN_BLK) ? blocksum[tid] : 0;
    s[tid] = v;
    for (int off = 1; off < 128; off <<= 1) {
        __syncthreads();
        int a = (tid >= off) ? s[tid - off] : 0;
        __syncthreads();
        s[tid] += a;
    }
    __syncthreads();
    if (tid < SCAN_BLK) blocksum[tid] = s[tid] - v;  // exclusive
    if (tid == 127) rowptr[NN] = s[127];             // total == NE
}

// phase 3: intra-block scan + block offset -> rowptr; zero deg_cnt (fill cursor)
__global__ __launch_bounds__(256) void scan_write_kernel(int* __restrict__ deg_cnt,
                                                         const int* __restrict__ blocksum,
                                                         int* __restrict__ rowptr) {
    __shared__ int s[256];
    int base = blockIdx.x * 1024 + threadIdx.x * 4;
    int4 v = make_int4(0, 0, 0, 0);
    if (base < NN) v = *(const int4*)(deg_cnt + base);
    int t = v.x + v.y + v.z + v.w;
    s[threadIdx.x] = t;
    for (int off = 1; off < 256; off <<= 1) {
        __syncthreads();
        int a = (threadIdx.x >= off) ? s[threadIdx.x - off] : 0;
        __syncthreads();
        s[threadIdx.x] += a;
    }
    __syncthreads();
    int pre = blocksum[blockIdx.x] + s[threadIdx.x] - t;  // exclusive prefix
    if (base < NN) {
        rowptr[base] = pre;
        rowptr[base + 1] = pre + v.x;
        rowptr[base + 2] = pre + v.x + v.y;
        rowptr[base + 3] = pre + v.x + v.y + v.z;
        *(int4*)(deg_cnt + base) = make_int4(0, 0, 0, 0);
    }
}

// ---------------- CSR fill: interleaved (src, weight) ----------------
__global__ __launch_bounds__(256) void fill_kernel(const int* __restrict__ ei,
                                                   const int* __restrict__ flags,
                                                   const float* __restrict__ dinv,
                                                   const int* __restrict__ rowptr,
                                                   int* __restrict__ cursor,
                                                   int2* __restrict__ csw) {
    int is32 = flags[0];
    int e = blockIdx.x * 256 + threadIdx.x;
    if (e >= NE) return;
    int s = ld_src(ei, e, is32), d = ld_dst(ei, e, is32);
    int pos = rowptr[d] + atomicAdd(&cursor[d], 1);
    float w = dinv[s] * dinv[d];
    csw[pos] = make_int2(s, __float_as_int(w));
}

// ---------------- t = h @ W  (W column register-resident per lane) ----------------
__global__ __launch_bounds__(256) void gemm_kernel(const float* __restrict__ h,
                                                   const float* __restrict__ W,
                                                   float* __restrict__ t) {
    int c = threadIdx.x & 63;
    float w[DD];
#pragma unroll
    for (int k = 0; k < DD; ++k) w[k] = W[k * DD + c];

    int wave = blockIdx.x * (blockDim.x >> 6) + (threadIdx.x >> 6);
    int nwaves = gridDim.x * (blockDim.x >> 6);
    for (int r = wave; r < NN; r += nwaves) {
        const float4* hrow = (const float4*)(h + (size_t)r * DD);
        float acc = 0.f;
#pragma unroll
        for (int kk = 0; kk < DD / 4; ++kk) {
            float4 hv = hrow[kk];  // wave-uniform -> cacheline broadcast
            acc += hv.x * w[4 * kk] + hv.y * w[4 * kk + 1] +
                   hv.z * w[4 * kk + 2] + hv.w * w[4 * kk + 3];
        }
        t[(size_t)r * DD + c] = acc;
    }
}

// ---------------- gather: agg = self + bias + neighbor sum; partial BN stats ----------------
__global__ __launch_bounds__(256) void gather_kernel(const float* __restrict__ t,
                                                     const float* __restrict__ dinv,
                                                     const float* __restrict__ bias,
                                                     const int* __restrict__ rowptr,
                                                     const int2* __restrict__ csw,
                                                     float* __restrict__ h,
                                                     float* __restrict__ part) {
    int f = threadIdx.x & 63;
    int wave = blockIdx.x * 4 + (threadIdx.x >> 6);
    float bb = bias[f];
    float sum = 0.f, sq = 0.f;
    for (int d = wave; d < NN; d += NBLK_GATHER * 4) {
        float di = dinv[d];
        float acc = t[d * DD + f] * di * di + bb;
        int j = rowptr[d], jend = rowptr[d + 1];
        for (; j + 4 <= jend; j += 4) {
            int2 a0 = csw[j], a1 = csw[j + 1], a2 = csw[j + 2], a3 = csw[j + 3];
            float v0 = t[a0.x * DD + f];
            float v1 = t[a1.x * DD + f];
            float v2 = t[a2.x * DD + f];
            float v3 = t[a3.x * DD + f];
            acc += v0 * __int_as_float(a0.y) + v1 * __int_as_float(a1.y) +
                   v2 * __int_as_float(a2.y) + v3 * __int_as_float(a3.y);
        }
        for (; j < jend; ++j) {
            int2 a = csw[j];
            acc += t[a.x * DD + f] * __int_as_float(a.y);
        }
        h[d * DD + f] = acc;
        sum += acc;
        sq += acc * acc;
    }
    __shared__ float s_sum[256], s_sq[256];
    s_sum[threadIdx.x] = sum;
    s_sq[threadIdx.x] = sq;
    __syncthreads();
    if (threadIdx.x < 64) {
        sum = s_sum[f] + s_sum[64 + f] + s_sum[128 + f] + s_sum[192 + f];
        sq = s_sq[f] + s_sq[64 + f] + s_sq[128 + f] + s_sq[192 + f];
        part[blockIdx.x * 128 + f] = sum;
        part[blockIdx.x * 128 + 64 + f] = sq;
    }
}

// ---------------- BN finalize: reduce partials -> scale/shift ----------------
__global__ __launch_bounds__(256) void bn_finalize_kernel(const float* __restrict__ part,
                                                          const float* __restrict__ gamma,
                                                          const float* __restrict__ beta,
                                                          float* __restrict__ stats_l) {
    __shared__ float s_sum[256], s_sq[256];
    int f = threadIdx.x & 63, g = threadIdx.x >> 6;
    float S = 0.f, Q = 0.f;
    for (int bk = g; bk < NBLK_GATHER; bk += 4) {
        S += part[bk * 128 + f];
        Q += part[bk * 128 + 64 + f];
    }
    s_sum[threadIdx.x] = S;
    s_sq[threadIdx.x] = Q;
    __syncthreads();
    if (threadIdx.x < 64) {
        S = s_sum[f] + s_sum[64 + f] + s_sum[128 + f] + s_sum[192 + f];
        Q = s_sq[f] + s_sq[64 + f] + s_sq[128 + f] + s_sq[192 + f];
        float mean = S / (float)NN;
        float var = fmaxf(Q / (float)NN - mean * mean, 0.f);
        float sc = gamma[f] * rsqrtf(var + BN_EPS);
        stats_l[f] = sc;
        stats_l[64 + f] = beta[f] - mean * sc;
    }
}

// ---------------- BN apply + ReLU (in place) ----------------
__global__ __launch_bounds__(256) void bn_apply_kernel(float* __restrict__ h,
                                                       const float* __restrict__ stats_l) {
    int i = blockIdx.x * 256 + threadIdx.x;
    if (i >= NN * DD) return;
    int f = i & 63;
    float v = h[i] * stats_l[f] + stats_l[64 + f];
    h[i] = fmaxf(v, 0.f);
}

// ---------------- pool: fused BN-apply(layer3) + ReLU + mean-pool + counts ----------------
#define POOL_CHUNK 512
__global__ __launch_bounds__(256) void pool_kernel(const float* __restrict__ hraw,
                                                   const float* __restrict__ stats_l,
                                                   const int* __restrict__ batch,
                                                   const int* __restrict__ flags,
                                                   float* __restrict__ pool,
                                                   float* __restrict__ counts) {
    int is32 = flags[1];
    int f = threadIdx.x & 63, rg = threadIdx.x >> 6;
    float sc = stats_l[f], sh = stats_l[64 + f];
    int base = blockIdx.x * POOL_CHUNK;
    float acc = 0.f, cnt = 0.f;
    int cur = -1;
    for (int i = rg; i < POOL_CHUNK; i += 4) {
        int n = base + i;
        if (n >= NN) break;
        int g = ld_batch(batch, n, is32);
        if (g != cur) {
            if (cur >= 0) {
                atomicAdd(&pool[cur * DD + f], acc);
                if (f == 0) atomicAdd(&counts[cur], cnt);
            }
            acc = 0.f;
            cnt = 0.f;
            cur = g;
        }
        acc += fmaxf(hraw[(size_t)n * DD + f] * sc + sh, 0.f);
        cnt += 1.f;
    }
    if (cur >= 0) {
        atomicAdd(&pool[cur * DD + f], acc);
        if (f == 0) atomicAdd(&counts[cur], cnt);
    }
}

__global__ __launch_bounds__(256) void final_kernel(const float* __restrict__ pool,
                                                    const float* __restrict__ counts,
                                                    float* __restrict__ out) {
    int i = blockIdx.x * 256 + threadIdx.x;
    if (i < NG * DD) {
        int g = i >> 6;
        out[i] = pool[i] / fmaxf(counts[g], 1.0f);
    }
}

extern "C" void kernel_launch(void* const* d_in, const int* in_sizes, int n_in,
                              void* d_out, int out_size, void* d_ws, size_t ws_size,
                              hipStream_t stream) {
    const float* x = (const float*)d_in[0];       // [NN, DD] f32
    const int* edge_index = (const int*)d_in[1];  // [2, NE] int (width detected)
    const int* batch = (const int*)d_in[2];       // [NN] int (width detected)
    const float* Ws = (const float*)d_in[3];      // [3,64,64]
    const float* bs = (const float*)d_in[4];      // [3,64]
    const float* gammas = (const float*)d_in[5];  // [3,64]
    const float* betas = (const float*)d_in[6];   // [3,64]
    float* out = (float*)d_out;                   // [NG, DD]

    // workspace layout (csw 8B-aligned; deg_cnt/rowptr 16B-aligned for int4)
    float* h = (float*)d_ws;                   // 6,400,000 f
    float* t = h + (size_t)NN * DD;            // 6,400,000 f
    int2* csw = (int2*)(t + (size_t)NN * DD);  // NE int2 (12.8 MB)
    float* dinv = (float*)(csw + NE);          // 100,000 f
    int* deg_cnt = (int*)(dinv + NN);          // 100,000 i (also fill cursor)
    int* rowptr = deg_cnt + NN;                // 100,001 i
    float* part = (float*)(rowptr + NN + 1);   // NBLK_GATHER*128 f
    float* stats = part + NBLK_GATHER * 128;   // 3*128 f (sc, sh per layer)
    float* pool = stats + NL * 128;            // 8192 f
    float* counts = pool + NG * DD;            // 128 f
    int* flags = (int*)(counts + NG);          // 2 i
    int* blocksum = flags + 2;                 // 128 i

    hipMemsetAsync(deg_cnt, 0, NN * sizeof(int), stream);
    hipMemsetAsync(pool, 0, (NG * DD + NG) * sizeof(float), stream);

    detect_kernel<<<1, 256, 0, stream>>>(edge_index, batch, flags);
    deg_kernel<<<(NE + 255) / 256, 256, 0, stream>>>(edge_index, flags, deg_cnt);
    dinv_kernel<<<(NN + 255) / 256, 256, 0, stream>>>(deg_cnt, dinv);
    scan_part_kernel<<<SCAN_BLK, 256, 0, stream>>>(deg_cnt, blocksum);
    scan_mid_kernel<<<1, 128, 0, stream>>>(blocksum, rowptr);
    scan_write_kernel<<<SCAN_BLK, 256, 0, stream>>>(deg_cnt, blocksum, rowptr);
    fill_kernel<<<(NE + 255) / 256, 256, 0, stream>>>(edge_index, flags, dinv, rowptr,
                                                      deg_cnt, csw);

    for (int l = 0; l < NL; ++l) {
        const float* hin = (l == 0) ? x : h;
        if (l > 0)
            bn_apply_kernel<<<(NN * DD + 255) / 256, 256, 0, stream>>>(h, stats + (l - 1) * 128);
        gemm_kernel<<<1600, 256, 0, stream>>>(hin, Ws + (size_t)l * DD * DD, t);
        gather_kernel<<<NBLK_GATHER, 256, 0, stream>>>(t, dinv, bs + l * DD, rowptr, csw, h, part);
        bn_finalize_kernel<<<1, 256, 0, stream>>>(part, gammas + l * DD, betas + l * DD,
                                                  stats + l * 128);
    }

    pool_kernel<<<(NN + POOL_CHUNK - 1) / POOL_CHUNK, 256, 0, stream>>>(
        h, stats + 2 * 128, batch, flags, pool, counts);
    final_kernel<<<(NG * DD + 255) / 256, 256, 0, stream>>>(pool, counts, out);
}

// Round 6
// 945.513 us; speedup vs baseline: 2.0470x; 1.2300x over previous
//
#include <hip/hip_runtime.h>

#define NN 100000
#define NE 1600000
#define DD 64
#define NL 3
#define NG 128
#define BN_EPS 1e-5f
#define NBLK_GATHER 2048
#define SCAN_BLK 98  // ceil(NN / 1024)

// ---------------- dtype detection: int64 vs int32 index arrays ----------------
__global__ __launch_bounds__(256) void detect_kernel(const int* __restrict__ ei,
                                                     const int* __restrict__ batch,
                                                     int* __restrict__ flags) {
    __shared__ int s_e, s_b;
    if (threadIdx.x == 0) { s_e = 0; s_b = 0; }
    __syncthreads();
    for (int i = threadIdx.x; i < 512; i += 256) {
        if (ei[2 * i + 1] != 0) atomicOr(&s_e, 1);
        if (batch[NN - 1024 + 2 * i + 1] != 0) atomicOr(&s_b, 1);
    }
    __syncthreads();
    if (threadIdx.x == 0) { flags[0] = s_e; flags[1] = s_b; }  // 1 = int32, 0 = int64
}

__device__ __forceinline__ int ld_src(const int* ei, int e, int is32) {
    return is32 ? ei[e] : ei[2 * e];
}
__device__ __forceinline__ int ld_dst(const int* ei, int e, int is32) {
    return is32 ? ei[NE + e] : ei[2 * NE + 2 * e];
}
__device__ __forceinline__ int ld_batch(const int* b, int n, int is32) {
    return is32 ? b[n] : b[2 * n];
}

// ---------------- degree (int) ----------------
__global__ __launch_bounds__(256) void deg_kernel(const int* __restrict__ ei,
                                                  const int* __restrict__ flags,
                                                  int* __restrict__ deg_cnt) {
    int is32 = flags[0];
    int e = blockIdx.x * 256 + threadIdx.x;
    if (e < NE) atomicAdd(&deg_cnt[ld_dst(ei, e, is32)], 1);
}

__global__ __launch_bounds__(256) void dinv_kernel(const int* __restrict__ deg_cnt,
                                                   float* __restrict__ dinv) {
    int i = blockIdx.x * 256 + threadIdx.x;
    if (i < NN) dinv[i] = rsqrtf((float)deg_cnt[i] + 1.0f);  // +1 self-loop
}

// ---------------- parallel exclusive scan of degrees -> rowptr ----------------
__global__ __launch_bounds__(256) void scan_part_kernel(const int* __restrict__ deg_cnt,
                                                        int* __restrict__ blocksum) {
    __shared__ int s[256];
    int base = blockIdx.x * 1024 + threadIdx.x * 4;
    int t = 0;
    if (base < NN) {  // NN % 4 == 0 -> whole int4 in-bounds
        int4 v = *(const int4*)(deg_cnt + base);
        t = v.x + v.y + v.z + v.w;
    }
    s[threadIdx.x] = t;
    __syncthreads();
    for (int off = 128; off > 0; off >>= 1) {
        if (threadIdx.x < off) s[threadIdx.x] += s[threadIdx.x + off];
        __syncthreads();
    }
    if (threadIdx.x == 0) blocksum[blockIdx.x] = s[0];
}

__global__ __launch_bounds__(128) void scan_mid_kernel(int* __restrict__ blocksum,
                                                       int* __restrict__ rowptr) {
    __shared__ int s[128];
    int tid = threadIdx.x;
    int v = (tid < SCAN_BLK) ? blocksum[tid] : 0;
    s[tid] = v;
    for (int off = 1; off < 128; off <<= 1) {
        __syncthreads();
        int a = (tid >= off) ? s[tid - off] : 0;
        __syncthreads();
        s[tid] += a;
    }
    __syncthreads();
    if (tid < SCAN_BLK) blocksum[tid] = s[tid] - v;  // exclusive
    if (tid == 127) rowptr[NN] = s[127];             // total == NE
}

__global__ __launch_bounds__(256) void scan_write_kernel(int* __restrict__ deg_cnt,
                                                         const int* __restrict__ blocksum,
                                                         int* __restrict__ rowptr) {
    __shared__ int s[256];
    int base = blockIdx.x * 1024 + threadIdx.x * 4;
    int4 v = make_int4(0, 0, 0, 0);
    if (base < NN) v = *(const int4*)(deg_cnt + base);
    int t = v.x + v.y + v.z + v.w;
    s[threadIdx.x] = t;
    for (int off = 1; off < 256; off <<= 1) {
        __syncthreads();
        int a = (threadIdx.x >= off) ? s[threadIdx.x - off] : 0;
        __syncthreads();
        s[threadIdx.x] += a;
    }
    __syncthreads();
    int pre = blocksum[blockIdx.x] + s[threadIdx.x] - t;  // exclusive prefix
    if (base < NN) {
        rowptr[base] = pre;
        rowptr[base + 1] = pre + v.x;
        rowptr[base + 2] = pre + v.x + v.y;
        rowptr[base + 3] = pre + v.x + v.y + v.z;
        *(int4*)(deg_cnt + base) = make_int4(0, 0, 0, 0);
    }
}

// ---------------- CSR fill: interleaved (src, weight) ----------------
__global__ __launch_bounds__(256) void fill_kernel(const int* __restrict__ ei,
                                                   const int* __restrict__ flags,
                                                   const float* __restrict__ dinv,
                                                   const int* __restrict__ rowptr,
                                                   int* __restrict__ cursor,
                                                   int2* __restrict__ csw) {
    int is32 = flags[0];
    int e = blockIdx.x * 256 + threadIdx.x;
    if (e >= NE) return;
    int s = ld_src(ei, e, is32), d = ld_dst(ei, e, is32);
    int pos = rowptr[d] + atomicAdd(&cursor[d], 1);
    float w = dinv[s] * dinv[d];
    csw[pos] = make_int2(s, __float_as_int(w));
}

// ---------------- t = h @ W; block 0 zero-inits this layer's BN accumulator ----------------
__global__ __launch_bounds__(256) void gemm_kernel(const float* __restrict__ h,
                                                   const float* __restrict__ W,
                                                   float* __restrict__ t,
                                                   float* __restrict__ accum_l) {
    if (blockIdx.x == 0 && threadIdx.x < 128) accum_l[threadIdx.x] = 0.f;

    int c = threadIdx.x & 63;
    float w[DD];
#pragma unroll
    for (int k = 0; k < DD; ++k) w[k] = W[k * DD + c];

    int wave = blockIdx.x * (blockDim.x >> 6) + (threadIdx.x >> 6);
    int nwaves = gridDim.x * (blockDim.x >> 6);
    for (int r = wave; r < NN; r += nwaves) {
        const float4* hrow = (const float4*)(h + (size_t)r * DD);
        float acc = 0.f;
#pragma unroll
        for (int kk = 0; kk < DD / 4; ++kk) {
            float4 hv = hrow[kk];  // wave-uniform -> cacheline broadcast
            acc += hv.x * w[4 * kk] + hv.y * w[4 * kk + 1] +
                   hv.z * w[4 * kk + 2] + hv.w * w[4 * kk + 3];
        }
        t[(size_t)r * DD + c] = acc;
    }
}

// ---------------- gather: agg = self + bias + neighbor sum; BN stats via atomics ----------------
__global__ __launch_bounds__(256) void gather_kernel(const float* __restrict__ t,
                                                     const float* __restrict__ dinv,
                                                     const float* __restrict__ bias,
                                                     const int* __restrict__ rowptr,
                                                     const int2* __restrict__ csw,
                                                     float* __restrict__ h,
                                                     float* __restrict__ accum_l) {
    int f = threadIdx.x & 63;
    int wave = blockIdx.x * 4 + (threadIdx.x >> 6);
    float bb = bias[f];
    float sum = 0.f, sq = 0.f;
    for (int d = wave; d < NN; d += NBLK_GATHER * 4) {
        float di = dinv[d];
        float acc = t[d * DD + f] * di * di + bb;
        int j = rowptr[d], jend = rowptr[d + 1];
        for (; j + 4 <= jend; j += 4) {
            int2 a0 = csw[j], a1 = csw[j + 1], a2 = csw[j + 2], a3 = csw[j + 3];
            float v0 = t[a0.x * DD + f];
            float v1 = t[a1.x * DD + f];
            float v2 = t[a2.x * DD + f];
            float v3 = t[a3.x * DD + f];
            acc += v0 * __int_as_float(a0.y) + v1 * __int_as_float(a1.y) +
                   v2 * __int_as_float(a2.y) + v3 * __int_as_float(a3.y);
        }
        for (; j < jend; ++j) {
            int2 a = csw[j];
            acc += t[a.x * DD + f] * __int_as_float(a.y);
        }
        h[d * DD + f] = acc;
        sum += acc;
        sq += acc * acc;
    }
    __shared__ float s_sum[256], s_sq[256];
    s_sum[threadIdx.x] = sum;
    s_sq[threadIdx.x] = sq;
    __syncthreads();
    if (threadIdx.x < 64) {
        sum = s_sum[f] + s_sum[64 + f] + s_sum[128 + f] + s_sum[192 + f];
        sq = s_sq[f] + s_sq[64 + f] + s_sq[128 + f] + s_sq[192 + f];
        atomicAdd(&accum_l[f], sum);
        atomicAdd(&accum_l[64 + f], sq);
    }
}

// ---------------- BN finalize: tiny, reads 128-float accumulator ----------------
__global__ __launch_bounds__(64) void bn_finalize_kernel(const float* __restrict__ accum_l,
                                                         const float* __restrict__ gamma,
                                                         const float* __restrict__ beta,
                                                         float* __restrict__ stats_l) {
    int f = threadIdx.x;
    float S = accum_l[f], Q = accum_l[64 + f];
    float mean = S / (float)NN;
    float var = fmaxf(Q / (float)NN - mean * mean, 0.f);
    float sc = gamma[f] * rsqrtf(var + BN_EPS);
    stats_l[f] = sc;
    stats_l[64 + f] = beta[f] - mean * sc;
}

// ---------------- BN apply + ReLU (in place) ----------------
__global__ __launch_bounds__(256) void bn_apply_kernel(float* __restrict__ h,
                                                       const float* __restrict__ stats_l) {
    int i = blockIdx.x * 256 + threadIdx.x;
    if (i >= NN * DD) return;
    int f = i & 63;
    float v = h[i] * stats_l[f] + stats_l[64 + f];
    h[i] = fmaxf(v, 0.f);
}

// ---------------- pool: fused BN-apply(layer3) + ReLU + mean-pool + counts ----------------
#define POOL_CHUNK 512
__global__ __launch_bounds__(256) void pool_kernel(const float* __restrict__ hraw,
                                                   const float* __restrict__ stats_l,
                                                   const int* __restrict__ batch,
                                                   const int* __restrict__ flags,
                                                   float* __restrict__ pool,
                                                   float* __restrict__ counts) {
    int is32 = flags[1];
    int f = threadIdx.x & 63, rg = threadIdx.x >> 6;
    float sc = stats_l[f], sh = stats_l[64 + f];
    int base = blockIdx.x * POOL_CHUNK;
    float acc = 0.f, cnt = 0.f;
    int cur = -1;
    for (int i = rg; i < POOL_CHUNK; i += 4) {
        int n = base + i;
        if (n >= NN) break;
        int g = ld_batch(batch, n, is32);
        if (g != cur) {
            if (cur >= 0) {
                atomicAdd(&pool[cur * DD + f], acc);
                if (f == 0) atomicAdd(&counts[cur], cnt);
            }
            acc = 0.f;
            cnt = 0.f;
            cur = g;
        }
        acc += fmaxf(hraw[(size_t)n * DD + f] * sc + sh, 0.f);
        cnt += 1.f;
    }
    if (cur >= 0) {
        atomicAdd(&pool[cur * DD + f], acc);
        if (f == 0) atomicAdd(&counts[cur], cnt);
    }
}

__global__ __launch_bounds__(256) void final_kernel(const float* __restrict__ pool,
                                                    const float* __restrict__ counts,
                                                    float* __restrict__ out) {
    int i = blockIdx.x * 256 + threadIdx.x;
    if (i < NG * DD) {
        int g = i >> 6;
        out[i] = pool[i] / fmaxf(counts[g], 1.0f);
    }
}

extern "C" void kernel_launch(void* const* d_in, const int* in_sizes, int n_in,
                              void* d_out, int out_size, void* d_ws, size_t ws_size,
                              hipStream_t stream) {
    const float* x = (const float*)d_in[0];       // [NN, DD] f32
    const int* edge_index = (const int*)d_in[1];  // [2, NE] int (width detected)
    const int* batch = (const int*)d_in[2];       // [NN] int (width detected)
    const float* Ws = (const float*)d_in[3];      // [3,64,64]
    const float* bs = (const float*)d_in[4];      // [3,64]
    const float* gammas = (const float*)d_in[5];  // [3,64]
    const float* betas = (const float*)d_in[6];   // [3,64]
    float* out = (float*)d_out;                   // [NG, DD]

    // workspace layout (csw 8B-aligned; deg_cnt/rowptr 16B-aligned for int4)
    float* h = (float*)d_ws;                   // 6,400,000 f
    float* t = h + (size_t)NN * DD;            // 6,400,000 f
    int2* csw = (int2*)(t + (size_t)NN * DD);  // NE int2 (12.8 MB)
    float* dinv = (float*)(csw + NE);          // 100,000 f
    int* deg_cnt = (int*)(dinv + NN);          // 100,000 i (also fill cursor)
    int* rowptr = deg_cnt + NN;                // 100,001 i
    float* accum = (float*)(rowptr + NN + 1);  // 3*128 f (BN sum/sumsq per layer)
    float* stats = accum + NL * 128;           // 3*128 f (sc, sh per layer)
    float* pool = stats + NL * 128;            // 8192 f
    float* counts = pool + NG * DD;            // 128 f
    int* flags = (int*)(counts + NG);          // 2 i
    int* blocksum = flags + 2;                 // 128 i

    hipMemsetAsync(deg_cnt, 0, NN * sizeof(int), stream);
    hipMemsetAsync(pool, 0, (NG * DD + NG) * sizeof(float), stream);

    detect_kernel<<<1, 256, 0, stream>>>(edge_index, batch, flags);
    deg_kernel<<<(NE + 255) / 256, 256, 0, stream>>>(edge_index, flags, deg_cnt);
    dinv_kernel<<<(NN + 255) / 256, 256, 0, stream>>>(deg_cnt, dinv);
    scan_part_kernel<<<SCAN_BLK, 256, 0, stream>>>(deg_cnt, blocksum);
    scan_mid_kernel<<<1, 128, 0, stream>>>(blocksum, rowptr);
    scan_write_kernel<<<SCAN_BLK, 256, 0, stream>>>(deg_cnt, blocksum, rowptr);
    fill_kernel<<<(NE + 255) / 256, 256, 0, stream>>>(edge_index, flags, dinv, rowptr,
                                                      deg_cnt, csw);

    for (int l = 0; l < NL; ++l) {
        const float* hin = (l == 0) ? x : h;
        if (l > 0)
            bn_apply_kernel<<<(NN * DD + 255) / 256, 256, 0, stream>>>(h, stats + (l - 1) * 128);
        gemm_kernel<<<1600, 256, 0, stream>>>(hin, Ws + (size_t)l * DD * DD, t, accum + l * 128);
        gather_kernel<<<NBLK_GATHER, 256, 0, stream>>>(t, dinv, bs + l * DD, rowptr, csw, h,
                                                       accum + l * 128);
        bn_finalize_kernel<<<1, 64, 0, stream>>>(accum + l * 128, gammas + l * DD,
                                                 betas + l * DD, stats + l * 128);
    }

    pool_kernel<<<(NN + POOL_CHUNK - 1) / POOL_CHUNK, 256, 0, stream>>>(
        h, stats + 2 * 128, batch, flags, pool, counts);
    final_kernel<<<(NG * DD + 255) / 256, 256, 0, stream>>>(pool, counts, out);
}